// Round 8
// baseline (110.171 us; speedup 1.0000x reference)
//
#include <hip/hip_runtime.h>

#define B_SZ 8192
#define C_SZ 1024
#define NCLS 100
#define INV_T 0.25f
#define NCH 8             // K chunks of 128 cols (256 B/row)
#define PSTR 256          // packed rows per class (m~82, max<<256)

typedef unsigned int uint32;

using bf16x8 = __attribute__((ext_vector_type(8))) short;
using f32x16 = __attribute__((ext_vector_type(16))) float;

// round-to-nearest-even fp32 -> bf16 (inputs are positive, finite)
__device__ __forceinline__ unsigned short f2bf(float f) {
    uint32 u = __float_as_uint(f);
    u = u + 0x7fffu + ((u >> 16) & 1u);
    return (unsigned short)(u >> 16);
}

__device__ __forceinline__ void gload16_lds(const void* g, void* l) {
    __builtin_amdgcn_global_load_lds(
        (const __attribute__((address_space(1))) uint32*)g,
        (__attribute__((address_space(3))) uint32*)l, 16, 0, 0);
}

// One block per row. Row -> CLASS-PACKED slot (atomicAdd on counts): the pair
// sum is permutation-invariant within a class, so packing here removes ALL
// row-gather scatter from the pair kernel (rounds 2-7: scatter service rate
// ~0.9 TB/s was the wall). t packed identically.
__global__ __launch_bounds__(256) void softmax_pack_kernel(
        const float* __restrict__ x, const int* __restrict__ target,
        uint32* __restrict__ probs_packed, float* __restrict__ t_packed,
        int* __restrict__ counts) {
    int row = blockIdx.x;
    int tid = threadIdx.x;
    __shared__ float red[12];
    __shared__ int s_slot;

    int lbl = target[row];
    if (lbl < 0) lbl = 0;
    if (lbl >= NCLS) lbl = NCLS - 1;           // defensive
    if (tid == 0) s_slot = atomicAdd(&counts[lbl], 1);

    const float4* xr = (const float4*)(x + (size_t)row * C_SZ);
    float4 v = xr[tid];
    v.x *= INV_T; v.y *= INV_T; v.z *= INV_T; v.w *= INV_T;

    int wid = tid >> 6;
    float m = fmaxf(fmaxf(v.x, v.y), fmaxf(v.z, v.w));
    #pragma unroll
    for (int o = 32; o >= 1; o >>= 1) m = fmaxf(m, __shfl_xor(m, o, 64));
    if ((tid & 63) == 0) red[wid] = m;
    __syncthreads();
    m = fmaxf(fmaxf(red[0], red[1]), fmaxf(red[2], red[3]));

    float4 e;
    e.x = __expf(v.x - m); e.y = __expf(v.y - m);
    e.z = __expf(v.z - m); e.w = __expf(v.w - m);
    float s = (e.x + e.y) + (e.z + e.w);
    #pragma unroll
    for (int o = 32; o >= 1; o >>= 1) s += __shfl_xor(s, o, 64);
    if ((tid & 63) == 0) red[4 + wid] = s;
    __syncthreads();
    float Z = (red[4] + red[5]) + (red[6] + red[7]);
    float rZ = 1.0f / Z;

    float4 p;
    p.x = e.x * rZ + 1e-8f; p.y = e.y * rZ + 1e-8f;
    p.z = e.z * rZ + 1e-8f; p.w = e.w * rZ + 1e-8f;

    int slot = s_slot & (PSTR - 1);            // defensive wrap (never hit: m<<256)
    uint2 packed;
    packed.x = ((uint32)f2bf(p.y) << 16) | (uint32)f2bf(p.x);
    packed.y = ((uint32)f2bf(p.w) << 16) | (uint32)f2bf(p.z);
    ((uint2*)(probs_packed + ((size_t)lbl * PSTR + slot) * (C_SZ / 2)))[tid] = packed;

    float pl = p.x * __logf(p.x) + p.y * __logf(p.y) +
               p.z * __logf(p.z) + p.w * __logf(p.w);
    #pragma unroll
    for (int o = 32; o >= 1; o >>= 1) pl += __shfl_xor(pl, o, 64);
    if ((tid & 63) == 0) red[8 + wid] = pl;
    __syncthreads();
    if (tid == 0)
        t_packed[lbl * PSTR + slot] =
            ((red[8] + red[9]) + (red[10] + red[11])) * (1.0f / C_SZ);
}

// One 512-thread block (8 waves) per CLASS. Strip rows are contiguous in the
// packed layout -> staging is pure sequential streaming (no gather, no lists).
// 3-deep chunk pipeline: 4 x 32 KB LDS buffers, counted vmcnt(12/8/4/0) + raw
// s_barrier (never drains the load queue until the tail). Upper-triangle
// tile-pairs only (one tile yields kl[i,j]^2 + kl[j,i]^2). Packed slots >= m
// hold poison; every contribution is predicated on il<m && jl<m (MFMA outputs
// are element-independent dots, so poison never contaminates valid entries).
__global__ __launch_bounds__(512, 1) void pair_kernel(
        const char* __restrict__ probs, const float* __restrict__ t,
        const int* __restrict__ counts,
        float* __restrict__ accum, int* __restrict__ done_ctr,
        float* __restrict__ out) {
    __shared__ char sbuf[4][32768];            // 128 KB
    __shared__ float s_tA[128], s_tB[128];
    __shared__ float s_wsum[8];

    int tid = threadIdx.x;
    int wv = tid >> 6;
    int ln = tid & 63;
    int l = ln & 31;
    int h = ln >> 5;
    int k = blockIdx.x;
    float lacc = 0.0f;

    int m = (k < NCLS) ? counts[k] : 0;
    if (m > PSTR) m = PSTR;                    // defensive (matches slot wrap)
    if (m >= 1) {
        int ng = (m + 127) >> 7;               // 1 for m<=128 (always, this data)
        int ngp = (ng == 1) ? 1 : 3;           // (0,0) | (0,0),(0,1),(1,1)
        const char* cls = probs + (size_t)k * PSTR * 2048;
        const float* tcls = t + k * PSTR;

        for (int gp = 0; gp < ngp; gp++) {
            int gi = (gp == 2) ? 1 : 0;
            int gj = (gp == 0) ? 0 : 1;
            bool same_strip = (gi == gj);

            __syncthreads();                   // prev gp done with s_t / sbuf
            if (tid < 128) s_tA[tid] = tcls[gi * 128 + tid];
            else if (tid < 256) s_tB[tid - 128] = tcls[gj * 128 + (tid - 128)];

            int rowsA = m - gi * 128; if (rowsA > 128) rowsA = 128;
            int rowsB = m - gj * 128; if (rowsB > 128) rowsB = 128;
            int ntA = (rowsA + 31) >> 5;
            int ntB = (rowsB + 31) >> 5;
            int P = same_strip ? (ntA * (ntA + 1)) / 2 : ntA * ntB;

            int tta[2], ttb[2], pv[2];
            #pragma unroll
            for (int slot = 0; slot < 2; slot++) {
                int p = wv + slot * 8;
                pv[slot] = (p < P);
                int pp = pv[slot] ? p : 0;
                int a = 0, b = 0;
                if (same_strip) {
                    int rem = pp, len = ntA;
                    while (rem >= len) { rem -= len; a++; len--; }
                    b = a + rem;
                } else { a = pp / ntB; b = pp % ntB; }
                tta[slot] = a; ttb[slot] = b;
            }

            // chunk-invariant per-lane staging addrs: XOR-swizzled SOURCE,
            // linear LDS dest (rule 21); read side mirrors the XOR.
            const char* gA[4];
            const char* gB[4];
            #pragma unroll
            for (int s = 0; s < 4; s++) {
                int row = s * 32 + wv * 4 + (ln >> 4);
                int c16 = ln & 15;
                int off = (c16 ^ (row & 7)) << 4;
                gA[s] = cls + ((size_t)(gi * 128 + row) << 11) + off;
                gB[s] = cls + ((size_t)(gj * 128 + row) << 11) + off;
            }

            __syncthreads();                   // s_t visible; sbuf free

            f32x16 acc[2] = {};
            #define COMPUTE_CH(bufA_, bufB_)                                     \
                _Pragma("unroll")                                                \
                for (int slot = 0; slot < 2; slot++) {                           \
                    if (pv[slot]) {                                              \
                        _Pragma("unroll")                                        \
                        for (int ks = 0; ks < 4; ks++) {                         \
                            int ca = ((2 * ks + h) ^ (l & 7)) << 4;              \
                            bf16x8 av = *(const bf16x8*)((bufA_) + (tta[slot] * 32 + l) * 256 + ca); \
                            bf16x8 bv = *(const bf16x8*)((bufB_) + (ttb[slot] * 32 + l) * 256 + ca); \
                            acc[slot] = __builtin_amdgcn_mfma_f32_32x32x16_bf16(av, bv, acc[slot], 0, 0, 0); \
                        }                                                        \
                    }                                                            \
                }

            if (same_strip) {
                #define STG_S(ch)                                                \
                    _Pragma("unroll")                                            \
                    for (int s = 0; s < 4; s++)                                  \
                        gload16_lds(gA[s] + ((ch) << 8),                         \
                                    &sbuf[(ch) & 3][s * 8192 + wv * 1024]);
                STG_S(0); STG_S(1); STG_S(2);          // 12 loads/wave in flight
                #pragma unroll 1
                for (int ch = 0; ch < NCH; ch++) {
                    if (ch + 3 < NCH) STG_S(ch + 3);   // 16 in flight
                    int rem = NCH - 1 - ch;
                    if (rem >= 3)      asm volatile("s_waitcnt vmcnt(12)" ::: "memory");
                    else if (rem == 2) asm volatile("s_waitcnt vmcnt(8)" ::: "memory");
                    else if (rem == 1) asm volatile("s_waitcnt vmcnt(4)" ::: "memory");
                    else               asm volatile("s_waitcnt vmcnt(0)" ::: "memory");
                    __builtin_amdgcn_sched_barrier(0);
                    __builtin_amdgcn_s_barrier();      // chunk ch fully in LDS
                    __builtin_amdgcn_sched_barrier(0);
                    COMPUTE_CH(sbuf[ch & 3], sbuf[ch & 3]);
                    __builtin_amdgcn_sched_barrier(0);
                    __builtin_amdgcn_s_barrier();      // reads done before reuse
                }
                #undef STG_S
            } else {
                #define STG_C(ch)                                                \
                    _Pragma("unroll")                                            \
                    for (int s = 0; s < 4; s++) {                                \
                        gload16_lds(gA[s] + ((ch) << 8),                         \
                                    &sbuf[(ch) & 1][s * 8192 + wv * 1024]);      \
                        gload16_lds(gB[s] + ((ch) << 8),                         \
                                    &sbuf[2 + ((ch) & 1)][s * 8192 + wv * 1024]); \
                    }
                STG_C(0);                              // 8 loads/wave in flight
                #pragma unroll 1
                for (int ch = 0; ch < NCH; ch++) {
                    if (ch + 1 < NCH) {
                        STG_C(ch + 1);                 // 16 in flight
                        asm volatile("s_waitcnt vmcnt(8)" ::: "memory");
                    } else {
                        asm volatile("s_waitcnt vmcnt(0)" ::: "memory");
                    }
                    __builtin_amdgcn_sched_barrier(0);
                    __builtin_amdgcn_s_barrier();
                    __builtin_amdgcn_sched_barrier(0);
                    COMPUTE_CH(sbuf[ch & 1], sbuf[2 + (ch & 1)]);
                    __builtin_amdgcn_sched_barrier(0);
                    __builtin_amdgcn_s_barrier();
                }
                #undef STG_C
            }
            #undef COMPUTE_CH

            // epilogue. D: col = lane&31 (B/j side), row = (g&3)+8*(g>>2)+4*h (A/i).
            // diag tile: kl[i,j]^2 each (i!=j); off-diag: both orientations.
            float local = 0.0f;
            #pragma unroll
            for (int slot = 0; slot < 2; slot++) {
                if (pv[slot]) {
                    bool dtile = same_strip && (tta[slot] == ttb[slot]);
                    int jloc = ttb[slot] * 32 + l;
                    int jl = gj * 128 + jloc;
                    bool jv = jl < m;
                    float tcol = s_tB[jloc];
                    #pragma unroll
                    for (int g = 0; g < 16; g++) {
                        int rowloc = (g & 3) + 8 * (g >> 2) + 4 * h;
                        int iloc = tta[slot] * 32 + rowloc;
                        int il = gi * 128 + iloc;
                        bool iv = il < m;
                        float c = acc[slot][g] * (1.0f / C_SZ);
                        if (dtile) {
                            if (iv && jv && il != jl) {
                                float kl = tcol - c; local += kl * kl;
                            }
                        } else {
                            if (iv && jv) {
                                float k1 = tcol - c;
                                float k2 = s_tA[iloc] - c;
                                local += k1 * k1 + k2 * k2;
                            }
                        }
                    }
                }
            }
            lacc += local;
        }
    }

    #pragma unroll
    for (int o = 32; o >= 1; o >>= 1) lacc += __shfl_xor(lacc, o, 64);
    __syncthreads();
    if (ln == 0) s_wsum[wv] = lacc;
    __syncthreads();
    if (tid == 0) {
        float tot = 0.0f;
        #pragma unroll
        for (int w = 0; w < 8; w++) tot += s_wsum[w];
        atomicAdd(accum, tot);
        __threadfence();
        if (atomicAdd(done_ctr, 1) == (int)gridDim.x - 1) {
            __threadfence();
            out[0] = atomicAdd(accum, 0.0f) * (1.0f / B_SZ);
        }
    }
}

extern "C" void kernel_launch(void* const* d_in, const int* in_sizes, int n_in,
                              void* d_out, int out_size, void* d_ws, size_t ws_size,
                              hipStream_t stream) {
    const float* x = (const float*)d_in[0];
    const int* target = (const int*)d_in[1];
    float* out = (float*)d_out;

    char* ws = (char*)d_ws;
    uint32* probs_packed = (uint32*)ws;                    // 100*256 rows * 2KB = 52.4 MB
    char* p = ws + (size_t)NCLS * PSTR * C_SZ * 2;
    float* t_packed = (float*)p;   p += NCLS * PSTR * 4;   // 100 KB
    char* ctrl = p;                                        // 1 KB zeroed control block
    int* counts = (int*)ctrl;                              // [0,512): counts
    float* accum = (float*)(ctrl + 512);                   // [512,516)
    int* done_ctr = (int*)(ctrl + 576);                    // [576,580)

    hipMemsetAsync(ctrl, 0, 1024, stream);
    softmax_pack_kernel<<<B_SZ, 256, 0, stream>>>(x, target, probs_packed,
                                                  t_packed, counts);
    pair_kernel<<<NCLS, 512, 0, stream>>>((const char*)probs_packed, t_packed,
                                          counts, accum, done_ctr, out);
}

// Round 9
// 96.660 us; speedup vs baseline: 1.1398x; 1.1398x over previous
//
#include <hip/hip_runtime.h>

#define B_SZ 8192
#define C_SZ 1024
#define NCLS 100
#define INV_T 0.25f
#define MAX_ITEMS 65536
#define NCH 8             // K chunks of 128 cols (256 B/row)
#define GRP 128           // rows per group: whole class (m~82) in one strip
#define PAIR_GRID 128

typedef unsigned int uint32;

using bf16x8 = __attribute__((ext_vector_type(8))) short;
using f32x16 = __attribute__((ext_vector_type(16))) float;

// round-to-nearest-even fp32 -> bf16 (inputs are positive, finite)
__device__ __forceinline__ unsigned short f2bf(float f) {
    uint32 u = __float_as_uint(f);
    u = u + 0x7fffu + ((u >> 16) & 1u);
    return (unsigned short)(u >> 16);
}

__device__ __forceinline__ void gload16_lds(const void* g, void* l) {
    __builtin_amdgcn_global_load_lds(
        (const __attribute__((address_space(1))) uint32*)g,
        (__attribute__((address_space(3))) uint32*)l, 16, 0, 0);
}

// Block 0: prep (zero accum/done, bucket rows by label, build (k,gi<=gj) 128-row
// group-pair item table). Blocks 1..B_SZ: row softmax(x/T)+1e-8 -> bf16, t[row].
// (Round 8 showed class-packed scattered writes regress softmax ~10us; keep the
// contiguous row-order write and gather in pair instead.)
__global__ __launch_bounds__(256) void softmax_prep_kernel(
        const float* __restrict__ x, const int* __restrict__ target,
        uint32* __restrict__ probs_bf, float* __restrict__ t,
        int* __restrict__ counts, int* __restrict__ lists,
        int* __restrict__ items, int* __restrict__ nitems,
        float* __restrict__ accum, int* __restrict__ done_ctr) {
    int tid = threadIdx.x;

    if (blockIdx.x == 0) {
        __shared__ int cnt[NCLS];
        __shared__ int tbase[NCLS];
        if (tid < NCLS) cnt[tid] = 0;
        if (tid == 0) { accum[0] = 0.0f; done_ctr[0] = 0; }
        __syncthreads();
        #pragma unroll 4
        for (int i = 0; i < B_SZ / 256; i++) {
            int r = i * 256 + tid;
            int lbl = target[r];
            if (lbl < 0) lbl = 0;
            if (lbl >= NCLS) lbl = NCLS - 1;   // defensive
            int slot = atomicAdd(&cnt[lbl], 1);
            lists[lbl * B_SZ + slot] = r;
        }
        __syncthreads();
        if (tid < NCLS) counts[tid] = cnt[tid];
        if (tid == 0) {
            int tot = 0;
            for (int k = 0; k < NCLS; k++) {
                int ng = (cnt[k] + GRP - 1) / GRP;
                tbase[k] = tot;
                tot += ng * (ng + 1) / 2;      // upper-triangle group pairs only
            }
            nitems[0] = tot;
        }
        __syncthreads();
        if (tid < NCLS) {
            int ng = (cnt[tid] + GRP - 1) / GRP;
            int base = tbase[tid];
            int z = 0;
            for (int a = 0; a < ng; a++)
                for (int b = a; b < ng; b++)
                    items[base + z++] = tid | (a << 8) | (b << 20);
        }
        return;
    }

    int row = blockIdx.x - 1;
    const float4* xr = (const float4*)(x + (size_t)row * C_SZ);
    float4 v = xr[tid];
    v.x *= INV_T; v.y *= INV_T; v.z *= INV_T; v.w *= INV_T;

    __shared__ float red[12];
    int wid = tid >> 6;

    float m = fmaxf(fmaxf(v.x, v.y), fmaxf(v.z, v.w));
    #pragma unroll
    for (int o = 32; o >= 1; o >>= 1) m = fmaxf(m, __shfl_xor(m, o, 64));
    if ((tid & 63) == 0) red[wid] = m;
    __syncthreads();
    m = fmaxf(fmaxf(red[0], red[1]), fmaxf(red[2], red[3]));

    float4 e;
    e.x = __expf(v.x - m); e.y = __expf(v.y - m);
    e.z = __expf(v.z - m); e.w = __expf(v.w - m);
    float s = (e.x + e.y) + (e.z + e.w);
    #pragma unroll
    for (int o = 32; o >= 1; o >>= 1) s += __shfl_xor(s, o, 64);
    if ((tid & 63) == 0) red[4 + wid] = s;
    __syncthreads();
    float Z = (red[4] + red[5]) + (red[6] + red[7]);
    float rZ = 1.0f / Z;

    float4 p;
    p.x = e.x * rZ + 1e-8f; p.y = e.y * rZ + 1e-8f;
    p.z = e.z * rZ + 1e-8f; p.w = e.w * rZ + 1e-8f;

    uint2 packed;
    packed.x = ((uint32)f2bf(p.y) << 16) | (uint32)f2bf(p.x);
    packed.y = ((uint32)f2bf(p.w) << 16) | (uint32)f2bf(p.z);
    ((uint2*)(probs_bf + (size_t)row * (C_SZ / 2)))[tid] = packed;

    float pl = p.x * __logf(p.x) + p.y * __logf(p.y) +
               p.z * __logf(p.z) + p.w * __logf(p.w);
    #pragma unroll
    for (int o = 32; o >= 1; o >>= 1) pl += __shfl_xor(pl, o, 64);
    if ((tid & 63) == 0) red[8 + wid] = pl;
    __syncthreads();
    if (tid == 0)
        t[row] = ((red[8] + red[9]) + (red[10] + red[11])) * (1.0f / C_SZ);
}

// One 512-thread block (8 waves) per (class, gi<=gj) 128-row group pair.
// Stage each group's rows ONCE per K-chunk (coalesced, 32KB/strip) and compute
// the UPPER-TRIANGLE tile-pairs only (one tile yields kl[i,j]^2 + kl[j,i]^2).
// Sync: raw s_barrier + per-wave counted vmcnt -- raw barrier does NOT drain
// vmcnt, so next chunks' global_load_lds stay in flight. R9 change vs R7: in
// the same-strip path (gi==gj, the only path for m<=128) the B half of the LDS
// double-buffer is unused -> reuse it as 2 extra chunk buffers (depth-3
// prefetch, 12 loads/wave in flight instead of 4, vmcnt(12/8/4/0)).
__global__ __launch_bounds__(512, 2) void pair_kernel(
        const char* __restrict__ probs, const float* __restrict__ t,
        const int* __restrict__ counts, const int* __restrict__ lists,
        const int* __restrict__ nitems, const int* __restrict__ items,
        float* __restrict__ accum, int* __restrict__ done_ctr,
        float* __restrict__ out) {
    __shared__ char sAB[2][2][32768];   // [dbuf][strip A/B][128 rows x 256 B] = 128 KB
    __shared__ int s_ridA[GRP];
    __shared__ int s_ridB[GRP];
    __shared__ float s_tA[GRP];
    __shared__ float s_tB[GRP];
    __shared__ float s_wsum[8];

    int tid = threadIdx.x;
    int wv = tid >> 6;
    int ln = tid & 63;
    int l = ln & 31;
    int h = ln >> 5;
    int NI = nitems[0];
    if (NI > MAX_ITEMS) NI = MAX_ITEMS;          // defensive
    float lacc = 0.0f;

    for (int it = blockIdx.x; it < NI; it += (int)gridDim.x) {
        int pk = items[it];
        int k = pk & 255;
        if (k >= NCLS) continue;                 // defensive
        int gi = (pk >> 8) & 0xfff;
        int gj = pk >> 20;
        int m = counts[k];
        if (m < 1) continue;                     // defensive
        if (m > B_SZ) m = B_SZ;
        bool same_strip = (gi == gj);

        __syncthreads();   // prev item done with LDS; drains vmcnt to 0 (exact counting)
        if (tid < GRP) {
            int which = gi * GRP + tid; if (which > m - 1) which = m - 1;
            int r = lists[k * B_SZ + which] & (B_SZ - 1);
            s_ridA[tid] = r;
            s_tA[tid] = t[r];
        } else if (tid < 2 * GRP) {
            int rb = tid - GRP;
            int which = gj * GRP + rb; if (which > m - 1) which = m - 1;
            int r = lists[k * B_SZ + which] & (B_SZ - 1);
            s_ridB[rb] = r;
            s_tB[rb] = t[r];
        }
        __syncthreads();   // rids visible; vmcnt drained again

        int rowsA = m - gi * GRP; if (rowsA > GRP) rowsA = GRP;
        int rowsB = m - gj * GRP; if (rowsB > GRP) rowsB = GRP;
        int ntA = (rowsA + 31) >> 5;
        int ntB = (rowsB + 31) >> 5;
        int P = same_strip ? (ntA * (ntA + 1)) / 2 : ntA * ntB;

        int tta[2], ttb[2], pv[2];
        #pragma unroll
        for (int slot = 0; slot < 2; slot++) {
            int p = wv + slot * 8;
            pv[slot] = (p < P);
            int pp = pv[slot] ? p : 0;
            int a = 0, b = 0;
            if (same_strip) {
                int rem = pp, len = ntA;
                while (rem >= len) { rem -= len; a++; len--; }
                b = a + rem;
            } else { a = pp / ntB; b = pp % ntB; }
            tta[slot] = a; ttb[slot] = b;
        }

        // chunk-invariant per-lane staging addrs: XOR-swizzled SOURCE,
        // linear LDS dest (rule 21); read side mirrors the XOR.
        const char* gA[4];
        const char* gB[4];
        #pragma unroll
        for (int s = 0; s < 4; s++) {
            int row = s * 32 + wv * 4 + (ln >> 4);
            int c16 = ln & 15;
            int off = (c16 ^ (row & 7)) << 4;
            gA[s] = probs + ((size_t)s_ridA[row] << 11) + off;
            gB[s] = probs + ((size_t)s_ridB[row] << 11) + off;
        }

        f32x16 acc[2] = {};
        #define COMPUTE_P(bufA_, bufB_)                                          \
            _Pragma("unroll")                                                    \
            for (int slot = 0; slot < 2; slot++) {                               \
                if (pv[slot]) {                                                  \
                    _Pragma("unroll")                                            \
                    for (int ks = 0; ks < 4; ks++) {                             \
                        int ca = ((2 * ks + h) ^ (l & 7)) << 4;                  \
                        bf16x8 av = *(const bf16x8*)((bufA_) + (tta[slot] * 32 + l) * 256 + ca); \
                        bf16x8 bv = *(const bf16x8*)((bufB_) + (ttb[slot] * 32 + l) * 256 + ca); \
                        acc[slot] = __builtin_amdgcn_mfma_f32_32x32x16_bf16(av, bv, acc[slot], 0, 0, 0); \
                    }                                                            \
                }                                                                \
            }

        if (same_strip) {
            // depth-3 single-strip pipeline over all four 32KB slabs
            char (*sb4)[32768] = (char(*)[32768])sAB;
            #define STG_S(ch)                                                    \
                _Pragma("unroll")                                                \
                for (int s = 0; s < 4; s++)                                      \
                    gload16_lds(gA[s] + ((ch) << 8),                             \
                                &sb4[(ch) & 3][s * 8192 + wv * 1024]);
            STG_S(0); STG_S(1); STG_S(2);          // 12 loads/wave in flight
            #pragma unroll 1
            for (int ch = 0; ch < NCH; ch++) {
                if (ch + 3 < NCH) STG_S(ch + 3);   // 16 in flight
                int rem = NCH - 1 - ch;
                if (rem >= 3)      asm volatile("s_waitcnt vmcnt(12)" ::: "memory");
                else if (rem == 2) asm volatile("s_waitcnt vmcnt(8)" ::: "memory");
                else if (rem == 1) asm volatile("s_waitcnt vmcnt(4)" ::: "memory");
                else               asm volatile("s_waitcnt vmcnt(0)" ::: "memory");
                __builtin_amdgcn_sched_barrier(0);
                __builtin_amdgcn_s_barrier();      // chunk ch fully in LDS
                __builtin_amdgcn_sched_barrier(0);
                COMPUTE_P(sb4[ch & 3], sb4[ch & 3]);
                __builtin_amdgcn_sched_barrier(0);
                __builtin_amdgcn_s_barrier();      // reads done before reuse
            }
            #undef STG_S
        } else {
            #define STG_C(ch)                                                    \
                _Pragma("unroll")                                                \
                for (int s = 0; s < 4; s++) {                                    \
                    gload16_lds(gA[s] + ((ch) << 8),                             \
                                &sAB[(ch) & 1][0][s * 8192 + wv * 1024]);        \
                    gload16_lds(gB[s] + ((ch) << 8),                             \
                                &sAB[(ch) & 1][1][s * 8192 + wv * 1024]);        \
                }
            STG_C(0);                              // 8 loads/wave in flight
            #pragma unroll 1
            for (int ch = 0; ch < NCH; ch++) {
                if (ch + 1 < NCH) {
                    STG_C(ch + 1);                 // 16 in flight
                    asm volatile("s_waitcnt vmcnt(8)" ::: "memory");
                } else {
                    asm volatile("s_waitcnt vmcnt(0)" ::: "memory");
                }
                __builtin_amdgcn_sched_barrier(0);
                __builtin_amdgcn_s_barrier();
                __builtin_amdgcn_sched_barrier(0);
                COMPUTE_P(sAB[ch & 1][0], sAB[ch & 1][1]);
                __builtin_amdgcn_sched_barrier(0);
                __builtin_amdgcn_s_barrier();
            }
            #undef STG_C
        }
        #undef COMPUTE_P

        // epilogue. D: col = lane&31 (B/j side), row = (g&3)+8*(g>>2)+4*h (A/i).
        // diag tile: kl[i,j]^2 each (i!=j); off-diag: both orientations.
        float local = 0.0f;
        #pragma unroll
        for (int slot = 0; slot < 2; slot++) {
            if (pv[slot]) {
                bool dtile = same_strip && (tta[slot] == ttb[slot]);
                int jloc = ttb[slot] * 32 + l;
                int jl = gj * GRP + jloc;
                bool jv = jl < m;
                float tcol = s_tB[jloc];
                #pragma unroll
                for (int g = 0; g < 16; g++) {
                    int rowloc = (g & 3) + 8 * (g >> 2) + 4 * h;
                    int iloc = tta[slot] * 32 + rowloc;
                    int il = gi * GRP + iloc;
                    bool iv = il < m;
                    float c = acc[slot][g] * (1.0f / C_SZ);
                    if (dtile) {
                        if (iv && jv && il != jl) {
                            float kl = tcol - c; local += kl * kl;
                        }
                    } else {
                        if (iv && jv) {
                            float k1 = tcol - c;
                            float k2 = s_tA[iloc] - c;
                            local += k1 * k1 + k2 * k2;
                        }
                    }
                }
            }
        }
        lacc += local;
    }

    #pragma unroll
    for (int o = 32; o >= 1; o >>= 1) lacc += __shfl_xor(lacc, o, 64);
    __syncthreads();
    if (ln == 0) s_wsum[wv] = lacc;
    __syncthreads();
    if (tid == 0) {
        float tot = 0.0f;
        #pragma unroll
        for (int w = 0; w < 8; w++) tot += s_wsum[w];
        atomicAdd(accum, tot);
        __threadfence();
        if (atomicAdd(done_ctr, 1) == (int)gridDim.x - 1) {
            __threadfence();
            out[0] = atomicAdd(accum, 0.0f) * (1.0f / B_SZ);
        }
    }
}

extern "C" void kernel_launch(void* const* d_in, const int* in_sizes, int n_in,
                              void* d_out, int out_size, void* d_ws, size_t ws_size,
                              hipStream_t stream) {
    const float* x = (const float*)d_in[0];
    const int* target = (const int*)d_in[1];
    float* out = (float*)d_out;

    char* ws = (char*)d_ws;
    uint32* probs_bf = (uint32*)ws;                                   // 16 MB (B*C bf16)
    char* p = ws + (size_t)B_SZ * C_SZ * 2;
    float* t = (float*)p;            p += B_SZ * 4;                   // 32 KB
    int* counts = (int*)p;           p += 128 * 4;                    // 512 B
    int* nitems = (int*)p;           p += 16;                         // 4 B (+pad)
    int* lists = (int*)p;            p += (size_t)NCLS * B_SZ * 4;    // 3.2 MB
    int* items = (int*)p;            p += MAX_ITEMS * 4;              // 256 KB
    float* accum = (float*)p;        p += 16;                         // 4 B (+pad)
    int* done_ctr = (int*)p;                                          // 4 B

    softmax_prep_kernel<<<B_SZ + 1, 256, 0, stream>>>(x, target, probs_bf, t,
                                                      counts, lists, items, nitems,
                                                      accum, done_ctr);
    pair_kernel<<<PAIR_GRID, 512, 0, stream>>>((const char*)probs_bf, t, counts,
                                               lists, nitems, items, accum,
                                               done_ctr, out);
}